// Round 1
// baseline (55.052 us; speedup 1.0000x reference)
//
#include <hip/hip_runtime.h>
#include <math.h>

// Problem constants (fixed by reference)
#define B 64
#define NI 1024
#define NO 1024
#define NC 10

#define OT 32                // o-tile per block
#define ISPLIT 8             // split of the i-reduction across blocks
#define ISEG (NI / ISPLIT)   // 128 i per block
#define IT 32                // i sub-tile staged in LDS

// Computes, for one layer, partial sums over an i-segment of:
//   h_part[b,o]  = sum_i  x[b,i] * fc[o,i] * (v[o,i] > 0)
//   s_part[b,o]  = sum_i  log(tanh(100*|x[b,i]|)) * (v[o,i] > 0)   (clamped at -1e30)
// Grid: (NO/OT) * ISPLIT = 256 blocks, 256 threads (4 waves).
__global__ __launch_bounds__(256) void harsanyi_partial(
    const float* __restrict__ in,   // [B][NI]
    const float* __restrict__ v,    // [NO][NI]
    const float* __restrict__ fc,   // [NO][NI]
    float* __restrict__ ph,         // [ISPLIT][B][NO]
    float* __restrict__ ps)         // [ISPLIT][B][NO]
{
    const int ob = blockIdx.x & (NO / OT - 1);   // 0..31
    const int is = blockIdx.x / (NO / OT);       // 0..7
    const int o0 = ob * OT;
    const int i0 = is * ISEG;
    const int t  = threadIdx.x;
    const int tx = t & 15;   // b-group: handles b = tx*4 .. tx*4+3
    const int ty = t >> 4;   // o-group: handles o = o0 + ty*2, +1

    __shared__ float xs[IT][B + 4];    // x transposed [i][b], +4 pad keeps f4 align & banks spread
    __shared__ float ls[IT][B + 4];    // log(tanh(100|x|)) transposed
    __shared__ float wf[IT][OT + 4];   // masked fc, [i][o]
    __shared__ float wm[IT][OT + 4];   // mask as float, [i][o]

    float ah[2][4] = {{0.f, 0.f, 0.f, 0.f}, {0.f, 0.f, 0.f, 0.f}};
    float as_[2][4] = {{0.f, 0.f, 0.f, 0.f}, {0.f, 0.f, 0.f, 0.f}};

    for (int it0 = 0; it0 < ISEG; it0 += IT) {
        __syncthreads();   // protect LDS reuse from previous iteration
        // stage activations (and their log-tanh) transposed into LDS; coalesced reads
        #pragma unroll
        for (int k = 0; k < (IT * B) / 256; ++k) {   // 8
            int f  = t + k * 256;
            int il = f & (IT - 1);
            int b  = f >> 5;
            float xv = in[b * NI + i0 + it0 + il];
            float th = tanhf(100.0f * fabsf(xv));
            xs[il][b] = xv;
            ls[il][b] = fmaxf(logf(th), -1e30f);    // log(0) = -inf -> -1e30 (finite)
        }
        // stage masked weights transposed into LDS; coalesced reads
        #pragma unroll
        for (int k = 0; k < (IT * OT) / 256; ++k) {  // 4
            int f  = t + k * 256;
            int il = f & (IT - 1);
            int oo = f >> 5;
            int gi = (o0 + oo) * NI + i0 + it0 + il;
            float vv = v[gi];
            float fv = fc[gi];
            bool m = vv > 0.0f;
            wf[il][oo] = m ? fv : 0.0f;
            wm[il][oo] = m ? 1.0f : 0.0f;
        }
        __syncthreads();
        #pragma unroll
        for (int i = 0; i < IT; ++i) {
            const float4 xv  = *(const float4*)&xs[i][tx * 4];
            const float4 lv  = *(const float4*)&ls[i][tx * 4];
            const float2 wfv = *(const float2*)&wf[i][ty * 2];
            const float2 wmv = *(const float2*)&wm[i][ty * 2];
            float xa[4]  = {xv.x, xv.y, xv.z, xv.w};
            float la[4]  = {lv.x, lv.y, lv.z, lv.w};
            float wfa[2] = {wfv.x, wfv.y};
            float wma[2] = {wmv.x, wmv.y};
            #pragma unroll
            for (int oo = 0; oo < 2; ++oo) {
                #pragma unroll
                for (int bb = 0; bb < 4; ++bb) {
                    ah[oo][bb]  = fmaf(wfa[oo], xa[bb], ah[oo][bb]);
                    as_[oo][bb] = fmaf(wma[oo], la[bb], as_[oo][bb]);   // 0 * -1e30 = 0: safe
                }
            }
        }
    }
    // write partials (float2 over the o pair)
    #pragma unroll
    for (int bb = 0; bb < 4; ++bb) {
        int b = tx * 4 + bb;
        int base = (is * B + b) * NO + o0 + ty * 2;
        float2 hv = {ah[0][bb], ah[1][bb]};
        float2 sv = {as_[0][bb], as_[1][bb]};
        *(float2*)&ph[base] = hv;
        *(float2*)&ps[base] = sv;
    }
}

// h[b,o] = relu( (sum_s ph) * exp(sum_s ps) )
__global__ __launch_bounds__(256) void harsanyi_final(
    const float* __restrict__ ph, const float* __restrict__ ps, float* __restrict__ h)
{
    int idx = blockIdx.x * 256 + threadIdx.x;   // b*NO + o
    float sh = 0.f, ss = 0.f;
    #pragma unroll
    for (int s = 0; s < ISPLIT; ++s) {
        sh += ph[s * (B * NO) + idx];
        ss += ps[s * (B * NO) + idx];
    }
    h[idx] = fmaxf(sh * expf(ss), 0.0f);
}

// y[b,c] = sum_o h0[b,o]*head0[c,o] + h1[b,o]*head1[c,o]; one wave per (b,c)
__global__ __launch_bounds__(256) void head_kernel(
    const float* __restrict__ h0, const float* __restrict__ hd0,
    const float* __restrict__ h1, const float* __restrict__ hd1,
    float* __restrict__ y)
{
    int gid  = blockIdx.x * 256 + threadIdx.x;
    int wave = gid >> 6;
    int lane = threadIdx.x & 63;
    if (wave >= B * NC) return;
    int b = wave / NC, c = wave - b * NC;
    float acc = 0.f;
    #pragma unroll 4
    for (int o = lane; o < NO; o += 64)
        acc = fmaf(h0[b * NO + o], hd0[c * NO + o],
              fmaf(h1[b * NO + o], hd1[c * NO + o], acc));
    #pragma unroll
    for (int off = 32; off > 0; off >>= 1)
        acc += __shfl_down(acc, off);
    if (lane == 0) y[b * NC + c] = acc;
}

extern "C" void kernel_launch(void* const* d_in, const int* in_sizes, int n_in,
                              void* d_out, int out_size, void* d_ws, size_t ws_size,
                              hipStream_t stream) {
    const float* x   = (const float*)d_in[0];
    const float* v0  = (const float*)d_in[1];
    const float* fc0 = (const float*)d_in[2];
    const float* hd0 = (const float*)d_in[3];
    const float* v1  = (const float*)d_in[4];
    const float* fc1 = (const float*)d_in[5];
    const float* hd1 = (const float*)d_in[6];
    float* y = (float*)d_out;

    char* ws = (char*)d_ws;
    const size_t PART = (size_t)ISPLIT * B * NO * sizeof(float);  // 2 MB
    float* ph = (float*)ws;
    float* ps = (float*)(ws + PART);
    float* h0 = (float*)(ws + 2 * PART);
    float* h1 = h0 + B * NO;
    // total ws use: 2*2MB + 0.5MB = 4.5 MB

    const int gridP = ISPLIT * (NO / OT);   // 256
    const int gridF = (B * NO) / 256;       // 256
    const int gridH = (B * NC * 64) / 256;  // 160

    // layer 0
    harsanyi_partial<<<gridP, 256, 0, stream>>>(x, v0, fc0, ph, ps);
    harsanyi_final<<<gridF, 256, 0, stream>>>(ph, ps, h0);
    // layer 1 (input = h0; partial buffers reused)
    harsanyi_partial<<<gridP, 256, 0, stream>>>(h0, v1, fc1, ph, ps);
    harsanyi_final<<<gridF, 256, 0, stream>>>(ph, ps, h1);
    // heads
    head_kernel<<<gridH, 256, 0, stream>>>(h0, hd0, h1, hd1, y);
}

// Round 2
// 43.045 us; speedup vs baseline: 1.2789x; 1.2789x over previous
//
#include <hip/hip_runtime.h>
#include <math.h>

// Problem constants
#define B 64
#define NI 1024
#define NO 1024
#define NC 10

#define ISPLIT 16            // i-reduction split across blocks
#define ISEG (NI / ISPLIT)   // 64 i per block
#define OT 32                // o-tile per block
#define IT 32                // i sub-tile (2 tiles per block, double-buffered)

typedef float f4 __attribute__((ext_vector_type(4)));

// lt[b,i] = log(tanh(100*|x[b,i]|)), clamped to -1e30 so 0*lt == 0 stays clean.
__global__ __launch_bounds__(256) void prep_lt(const float* __restrict__ x,
                                               float* __restrict__ lt) {
    int f = (blockIdx.x * 256 + threadIdx.x) * 4;
    f4 xv = *(const f4*)&x[f];
    f4 o;
    #pragma unroll
    for (int j = 0; j < 4; ++j)
        o[j] = fmaxf(logf(tanhf(100.0f * fabsf(xv[j]))), -1e30f);
    *(f4*)&lt[f] = o;
}

// Partial sums over one i-segment:
//   ph[is,b,o] = sum_i x[b,i]*fc[o,i]*(v[o,i]>0)
//   ps[is,b,o] = sum_i lt[b,i]*(v[o,i]>0)
// Grid: 32 o-blocks * 16 i-splits = 512 blocks, 256 threads (2 blocks/CU).
__global__ __launch_bounds__(256, 2) void harsanyi_partial(
    const float* __restrict__ in,   // [B][NI]
    const float* __restrict__ lt,   // [B][NI] precomputed log-tanh
    const float* __restrict__ v,    // [NO][NI]
    const float* __restrict__ fc,   // [NO][NI]
    float* __restrict__ ph,         // [ISPLIT][B][NO]
    float* __restrict__ ps)         // [ISPLIT][B][NO]
{
    const int ob = blockIdx.x & 31;
    const int is = blockIdx.x >> 5;
    const int o0 = ob * OT, i0 = is * ISEG;
    const int t  = threadIdx.x;

    // double-buffered LDS tiles, transposed [i][b] / [i][o]; 17/9 f4 rows avoid
    // power-of-2 strides (2-way max on reads = free per m136)
    __shared__ f4 xs[2][IT][17];
    __shared__ f4 ls[2][IT][17];
    __shared__ f4 wf[2][IT][9];
    __shared__ f4 wm[2][IT][9];

    const int rb = t >> 3;          // 0..31: row (b or o) within 32-group
    const int ic = (t & 7) * 4;     // 0..28: i column

    // ---- issue ALL global loads upfront (12 x float4 / thread) ----
    f4 xr[2][2], lr[2][2], fr[2], vr[2];
    #pragma unroll
    for (int tt = 0; tt < 2; ++tt) {
        #pragma unroll
        for (int r = 0; r < 2; ++r) {
            int b = rb + 32 * r;
            xr[tt][r] = *(const f4*)&in[b * NI + i0 + tt * IT + ic];
            lr[tt][r] = *(const f4*)&lt[b * NI + i0 + tt * IT + ic];
        }
        fr[tt] = *(const f4*)&fc[(o0 + rb) * NI + i0 + tt * IT + ic];
        vr[tt] = *(const f4*)&v [(o0 + rb) * NI + i0 + tt * IT + ic];
    }

    const int tx = t & 15;   // b-group: b = tx*4..tx*4+3
    const int ty = t >> 4;   // o-group: o = o0 + ty*2, +1

    float ah[2][4] = {{0,0,0,0},{0,0,0,0}};
    float as_[2][4] = {{0,0,0,0},{0,0,0,0}};

#define STAGE(tt, bf) do {                                                  \
    float* xp = (float*)&xs[bf][0][0];                                      \
    float* lp = (float*)&ls[bf][0][0];                                      \
    float* fp = (float*)&wf[bf][0][0];                                      \
    float* mp = (float*)&wm[bf][0][0];                                      \
    _Pragma("unroll") for (int j = 0; j < 4; ++j) {                         \
        int il = ic + j;                                                    \
        _Pragma("unroll") for (int r = 0; r < 2; ++r) {                     \
            xp[il * 68 + rb + 32 * r] = xr[tt][r][j];                       \
            lp[il * 68 + rb + 32 * r] = lr[tt][r][j];                       \
        }                                                                   \
        bool m = vr[tt][j] > 0.0f;                                          \
        fp[il * 36 + rb] = m ? fr[tt][j] : 0.0f;                            \
        mp[il * 36 + rb] = m ? 1.0f : 0.0f;                                 \
    }                                                                       \
} while (0)

#define COMP(bf) do {                                                       \
    _Pragma("unroll") for (int i = 0; i < IT; ++i) {                        \
        f4 xv = xs[bf][i][tx];                                              \
        f4 lv = ls[bf][i][tx];                                              \
        float2 wfv = ((float2*)&wf[bf][i][0])[ty];                          \
        float2 wmv = ((float2*)&wm[bf][i][0])[ty];                          \
        float wfa[2] = {wfv.x, wfv.y};                                      \
        float wma[2] = {wmv.x, wmv.y};                                      \
        _Pragma("unroll") for (int oo = 0; oo < 2; ++oo)                    \
            _Pragma("unroll") for (int bb = 0; bb < 4; ++bb) {              \
                ah[oo][bb]  = fmaf(wfa[oo], xv[bb], ah[oo][bb]);            \
                as_[oo][bb] = fmaf(wma[oo], lv[bb], as_[oo][bb]);           \
            }                                                               \
    }                                                                       \
} while (0)

    STAGE(0, 0);
    __syncthreads();
    STAGE(1, 1);     // write buf1 while (below) reading buf0 — no barrier needed
    COMP(0);
    __syncthreads();
    COMP(1);

    #pragma unroll
    for (int bb = 0; bb < 4; ++bb) {
        int b = tx * 4 + bb;
        int base = (is * B + b) * NO + o0 + ty * 2;
        float2 hv = {ah[0][bb], ah[1][bb]};
        float2 sv = {as_[0][bb], as_[1][bb]};
        *(float2*)&ph[base] = hv;
        *(float2*)&ps[base] = sv;
    }
}

// h[b,o] = relu((sum_s ph) * exp(sum_s ps)); optionally also lt(h) for next layer
__global__ __launch_bounds__(256) void harsanyi_final(
    const float* __restrict__ ph, const float* __restrict__ ps,
    float* __restrict__ h, float* __restrict__ ltout)
{
    int idx = blockIdx.x * 256 + threadIdx.x;
    float sh = 0.f, ss = 0.f;
    #pragma unroll
    for (int s = 0; s < ISPLIT; ++s) {
        sh += ph[s * (B * NO) + idx];
        ss += ps[s * (B * NO) + idx];
    }
    float hv = fmaxf(sh * expf(ss), 0.0f);
    h[idx] = hv;
    if (ltout) ltout[idx] = fmaxf(logf(tanhf(100.0f * hv)), -1e30f);
}

// y[b,c] = sum_o h0[b,o]*head0[c,o] + h1[b,o]*head1[c,o]; one wave per (b,c)
__global__ __launch_bounds__(256) void head_kernel(
    const float* __restrict__ h0, const float* __restrict__ hd0,
    const float* __restrict__ h1, const float* __restrict__ hd1,
    float* __restrict__ y)
{
    int gid  = blockIdx.x * 256 + threadIdx.x;
    int wave = gid >> 6;
    int lane = threadIdx.x & 63;
    if (wave >= B * NC) return;
    int b = wave / NC, c = wave - b * NC;
    float acc = 0.f;
    #pragma unroll 4
    for (int o = lane; o < NO; o += 64)
        acc = fmaf(h0[b * NO + o], hd0[c * NO + o],
              fmaf(h1[b * NO + o], hd1[c * NO + o], acc));
    #pragma unroll
    for (int off = 32; off > 0; off >>= 1)
        acc += __shfl_down(acc, off);
    if (lane == 0) y[b * NC + c] = acc;
}

extern "C" void kernel_launch(void* const* d_in, const int* in_sizes, int n_in,
                              void* d_out, int out_size, void* d_ws, size_t ws_size,
                              hipStream_t stream) {
    const float* x   = (const float*)d_in[0];
    const float* v0  = (const float*)d_in[1];
    const float* fc0 = (const float*)d_in[2];
    const float* hd0 = (const float*)d_in[3];
    const float* v1  = (const float*)d_in[4];
    const float* fc1 = (const float*)d_in[5];
    const float* hd1 = (const float*)d_in[6];
    float* y = (float*)d_out;

    char* ws = (char*)d_ws;
    const size_t PART = (size_t)ISPLIT * B * NO * sizeof(float);  // 4 MB
    const size_t ACT  = (size_t)B * NO * sizeof(float);           // 256 KB
    float* ph  = (float*)ws;
    float* ps  = (float*)(ws + PART);
    float* lt0 = (float*)(ws + 2 * PART);
    float* lt1 = (float*)(ws + 2 * PART + ACT);
    float* h0  = (float*)(ws + 2 * PART + 2 * ACT);
    float* h1  = (float*)(ws + 2 * PART + 3 * ACT);
    // ws use: 8 MB + 1 MB

    const int gridP = ISPLIT * (NO / OT);    // 512
    const int gridF = (B * NO) / 256;        // 256
    const int gridH = (B * NC * 64) / 256;   // 160

    prep_lt<<<(B * NI) / 1024, 256, 0, stream>>>(x, lt0);                 // 64 blocks
    harsanyi_partial<<<gridP, 256, 0, stream>>>(x, lt0, v0, fc0, ph, ps);
    harsanyi_final<<<gridF, 256, 0, stream>>>(ph, ps, h0, lt1);           // h0 + lt(h0)
    harsanyi_partial<<<gridP, 256, 0, stream>>>(h0, lt1, v1, fc1, ph, ps);
    harsanyi_final<<<gridF, 256, 0, stream>>>(ph, ps, h1, nullptr);
    head_kernel<<<gridH, 256, 0, stream>>>(h0, hd0, h1, hd1, y);
}